// Round 1
// baseline (1568.456 us; speedup 1.0000x reference)
//
#include <hip/hip_runtime.h>

#define WPB 4  // waves per block (256 threads)

// ---------------- degree count ----------------
__global__ void gnn_deg_count(const int* __restrict__ dst, int* __restrict__ degi, int E) {
    int e = blockIdx.x * blockDim.x + threadIdx.x;
    if (e < E) atomicAdd(&degi[dst[e]], 1);
}

// ---------------- exclusive scan of degrees -> row_ptr, cursor, inv_deg ----------------
__global__ __launch_bounds__(1024) void gnn_scan(const int* __restrict__ degi,
                                                 int* __restrict__ row_ptr,
                                                 int* __restrict__ cursor,
                                                 float* __restrict__ inv_deg, int n) {
    const int PT = 8;
    __shared__ int wsum[16];
    __shared__ int carry_s;
    int tid = threadIdx.x, lane = tid & 63, wv = tid >> 6;
    if (tid == 0) carry_s = 0;
    __syncthreads();
    const int chunk = 1024 * PT;
    for (int base = 0; base < n; base += chunk) {
        int vals[PT];
        int run = 0;
        int i0 = base + tid * PT;
#pragma unroll
        for (int j = 0; j < PT; j++) {
            int idx = i0 + j;
            int v = (idx < n) ? degi[idx] : 0;
            run += v;
            vals[j] = run;  // inclusive within thread
        }
        int x = run;
#pragma unroll
        for (int off = 1; off < 64; off <<= 1) {
            int y = __shfl_up(x, off);
            if (lane >= off) x += y;
        }
        if (lane == 63) wsum[wv] = x;
        __syncthreads();
        int wave_excl = 0;
        for (int w = 0; w < wv; w++) wave_excl += wsum[w];
        int total = 0;
        for (int w = 0; w < 16; w++) total += wsum[w];
        int texcl = carry_s + wave_excl + (x - run);
        __syncthreads();
        if (tid == 0) carry_s += total;
#pragma unroll
        for (int j = 0; j < PT; j++) {
            int idx = i0 + j;
            if (idx < n) {
                int prev = (j == 0) ? 0 : vals[j - 1];
                int excl = texcl + prev;
                row_ptr[idx] = excl;
                cursor[idx] = excl;
                int v = vals[j] - prev;
                inv_deg[idx] = 1.0f / (float)(v > 1 ? v : 1);
            }
        }
        __syncthreads();
    }
    if (threadIdx.x == 0) row_ptr[n] = carry_s;
}

// ---------------- CSR fill (counting sort by dst) ----------------
__global__ void gnn_csr_fill(const int* __restrict__ src, const int* __restrict__ dst,
                             int* __restrict__ cursor, int* __restrict__ csr_src, int E) {
    int e = blockIdx.x * blockDim.x + threadIdx.x;
    if (e < E) {
        int d = dst[e];
        int p = atomicAdd(&cursor[d], 1);
        csr_src[p] = src[e];
    }
}

// ---------------- fused SAGE layer: mean-agg + lin_l + lin_r + bias + relu ----------------
// one wave per node, lane = feature
__global__ __launch_bounds__(256) void gnn_sage(const float* __restrict__ hin,
                                                float* __restrict__ hout,
                                                const int* __restrict__ row_ptr,
                                                const int* __restrict__ csr_src,
                                                const float* __restrict__ inv_deg,
                                                const float* __restrict__ Wl,
                                                const float* __restrict__ bl,
                                                const float* __restrict__ Wr, int n) {
    __shared__ float2 Wc[64 * 64];  // interleaved {Wl, Wr} -> 32 KiB
    int tid = threadIdx.x;
    for (int i = tid; i < 4096; i += 256) {
        Wc[i].x = Wl[i];
        Wc[i].y = Wr[i];
    }
    __syncthreads();
    int lane = tid & 63, wv = tid >> 6;
    int gw = blockIdx.x * WPB + wv;
    int nw = gridDim.x * WPB;
    for (int nd = gw; nd < n; nd += nw) {
        int s0 = row_ptr[nd], s1 = row_ptr[nd + 1];
        float acc = 0.0f;
        int e = s0;
        for (; e + 1 < s1; e += 2) {
            int sa = csr_src[e];
            int sb = csr_src[e + 1];
            float va = hin[(size_t)sa * 64 + lane];
            float vb = hin[(size_t)sb * 64 + lane];
            acc += va;
            acc += vb;
        }
        if (e < s1) {
            int sa = csr_src[e];
            acc += hin[(size_t)sa * 64 + lane];
        }
        acc *= inv_deg[nd];
        float hr = hin[(size_t)nd * 64 + lane];
        float out = bl[lane];
#pragma unroll
        for (int k = 0; k < 64; k++) {
            float a = __shfl(acc, k);
            float h2 = __shfl(hr, k);
            float2 w = Wc[k * 64 + lane];
            out += a * w.x + h2 * w.y;
        }
        hout[(size_t)nd * 64 + lane] = fmaxf(out, 0.0f);
    }
}

// ---------------- global mean pool (batch is sorted) ----------------
__global__ __launch_bounds__(256) void gnn_pool(const float* __restrict__ h,
                                                const int* __restrict__ batch,
                                                float* __restrict__ gsum,
                                                float* __restrict__ gcnt, int n) {
    int lane = threadIdx.x & 63, wv = threadIdx.x >> 6;
    int gw = blockIdx.x * WPB + wv;
    int start = gw * 64;
    if (start >= n) return;
    int cnt_here = min(64, n - start);
    int bi = start + lane;
    if (bi >= n) bi = n - 1;
    int myb = batch[bi];
    float acc = 0.0f;
    int cnt = 0;
    int cur = __shfl(myb, 0);
    for (int i = 0; i < cnt_here; i++) {
        int g = __shfl(myb, i);
        if (g != cur) {
            atomicAdd(&gsum[cur * 64 + lane], acc);
            if (lane == 0) atomicAdd(&gcnt[cur], (float)cnt);
            acc = 0.0f;
            cnt = 0;
            cur = g;
        }
        acc += h[(size_t)(start + i) * 64 + lane];
        cnt++;
    }
    atomicAdd(&gsum[cur * 64 + lane], acc);
    if (lane == 0) atomicAdd(&gcnt[cur], (float)cnt);
}

// ---------------- head: mean, relu(g@l0W+b), @outW+b ----------------
__global__ __launch_bounds__(256) void gnn_head(const float* __restrict__ gsum,
                                                const float* __restrict__ gcnt,
                                                const float* __restrict__ l0W,
                                                const float* __restrict__ l0b,
                                                const float* __restrict__ outW,
                                                const float* __restrict__ outb,
                                                float* __restrict__ out, int G, int OUT) {
    __shared__ float gm[64 * 64];
    __shared__ float t2[64 * 64];
    int tid = threadIdx.x;
    for (int i = tid; i < G * 64; i += 256) {
        int r = i >> 6;
        gm[i] = gsum[i] / fmaxf(gcnt[r], 1.0f);
    }
    __syncthreads();
    for (int i = tid; i < G * 64; i += 256) {
        int r = i >> 6, c = i & 63;
        float s = l0b[c];
#pragma unroll 8
        for (int k = 0; k < 64; k++) s += gm[(r << 6) + k] * l0W[(k << 6) + c];
        t2[i] = fmaxf(s, 0.0f);
    }
    __syncthreads();
    for (int i = tid; i < G * OUT; i += 256) {
        int r = i / OUT, c = i - r * OUT;
        float s = outb[c];
#pragma unroll 8
        for (int k = 0; k < 64; k++) s += t2[(r << 6) + k] * outW[k * OUT + c];
        out[i] = s;
    }
}

extern "C" void kernel_launch(void* const* d_in, const int* in_sizes, int n_in,
                              void* d_out, int out_size, void* d_ws, size_t ws_size,
                              hipStream_t stream) {
    const float* x = (const float*)d_in[0];
    const int* ei = (const int*)d_in[1];
    const int* batch = (const int*)d_in[2];
    const float* Wl[3] = {(const float*)d_in[3], (const float*)d_in[6], (const float*)d_in[9]};
    const float* bl[3] = {(const float*)d_in[4], (const float*)d_in[7], (const float*)d_in[10]};
    const float* Wr[3] = {(const float*)d_in[5], (const float*)d_in[8], (const float*)d_in[11]};
    const float* l0W = (const float*)d_in[12];
    const float* l0b = (const float*)d_in[13];
    const float* outW = (const float*)d_in[14];
    const float* outb = (const float*)d_in[15];

    int N = in_sizes[2];
    int E = in_sizes[1] / 2;
    int OUT = 10;
    int G = out_size / OUT;
    const int* src = ei;
    const int* dst = ei + E;

    char* ws = (char*)d_ws;
    size_t off = 0;
    auto alloc = [&](size_t b) -> char* {
        char* p = ws + off;
        off = (off + b + 255) & ~(size_t)255;
        return p;
    };
    int* degi = (int*)alloc((size_t)N * 4);
    int* row_ptr = (int*)alloc((size_t)(N + 1) * 4);
    int* cursor = (int*)alloc((size_t)N * 4);
    int* csr_src = (int*)alloc((size_t)E * 4);
    float* inv_deg = (float*)alloc((size_t)N * 4);
    float* hA = (float*)alloc((size_t)N * 64 * 4);
    float* hB = (float*)alloc((size_t)N * 64 * 4);
    float* gsum = (float*)alloc((size_t)G * 64 * 4);
    float* gcnt = (float*)alloc((size_t)G * 4);

    hipMemsetAsync(degi, 0, (size_t)N * 4, stream);
    hipMemsetAsync(gsum, 0, (size_t)G * 64 * 4, stream);
    hipMemsetAsync(gcnt, 0, (size_t)G * 4, stream);

    gnn_deg_count<<<(E + 255) / 256, 256, 0, stream>>>(dst, degi, E);
    gnn_scan<<<1, 1024, 0, stream>>>(degi, row_ptr, cursor, inv_deg, N);
    gnn_csr_fill<<<(E + 255) / 256, 256, 0, stream>>>(src, dst, cursor, csr_src, E);

    gnn_sage<<<1024, 256, 0, stream>>>(x, hA, row_ptr, csr_src, inv_deg, Wl[0], bl[0], Wr[0], N);
    gnn_sage<<<1024, 256, 0, stream>>>(hA, hB, row_ptr, csr_src, inv_deg, Wl[1], bl[1], Wr[1], N);
    gnn_sage<<<1024, 256, 0, stream>>>(hB, hA, row_ptr, csr_src, inv_deg, Wl[2], bl[2], Wr[2], N);

    int pool_blocks = ((N + 63) / 64 + WPB - 1) / WPB;
    gnn_pool<<<pool_blocks, 256, 0, stream>>>(hA, batch, gsum, gcnt, N);
    gnn_head<<<1, 256, 0, stream>>>(gsum, gcnt, l0W, l0b, outW, outb, (float*)d_out, G, OUT);
}

// Round 2
// 1286.926 us; speedup vs baseline: 1.2188x; 1.2188x over previous
//
#include <hip/hip_runtime.h>

#define WPB 4  // waves per block (256 threads)

// ---------------- degree count ----------------
__global__ void gnn_deg_count(const int* __restrict__ dst, int* __restrict__ degi, int E) {
    int e = blockIdx.x * blockDim.x + threadIdx.x;
    if (e < E) atomicAdd(&degi[dst[e]], 1);
}

// ---------------- exclusive scan of degrees -> row_ptr, cursor, inv_deg ----------------
__global__ __launch_bounds__(1024) void gnn_scan(const int* __restrict__ degi,
                                                 int* __restrict__ row_ptr,
                                                 int* __restrict__ cursor,
                                                 float* __restrict__ inv_deg, int n) {
    const int PT = 8;
    __shared__ int wsum[16];
    __shared__ int carry_s;
    int tid = threadIdx.x, lane = tid & 63, wv = tid >> 6;
    if (tid == 0) carry_s = 0;
    __syncthreads();
    const int chunk = 1024 * PT;
    for (int base = 0; base < n; base += chunk) {
        int vals[PT];
        int run = 0;
        int i0 = base + tid * PT;
#pragma unroll
        for (int j = 0; j < PT; j++) {
            int idx = i0 + j;
            int v = (idx < n) ? degi[idx] : 0;
            run += v;
            vals[j] = run;  // inclusive within thread
        }
        int x = run;
#pragma unroll
        for (int off = 1; off < 64; off <<= 1) {
            int y = __shfl_up(x, off);
            if (lane >= off) x += y;
        }
        if (lane == 63) wsum[wv] = x;
        __syncthreads();
        int wave_excl = 0;
        for (int w = 0; w < wv; w++) wave_excl += wsum[w];
        int total = 0;
        for (int w = 0; w < 16; w++) total += wsum[w];
        int texcl = carry_s + wave_excl + (x - run);
        __syncthreads();
        if (tid == 0) carry_s += total;
#pragma unroll
        for (int j = 0; j < PT; j++) {
            int idx = i0 + j;
            if (idx < n) {
                int prev = (j == 0) ? 0 : vals[j - 1];
                int excl = texcl + prev;
                row_ptr[idx] = excl;
                cursor[idx] = excl;
                int v = vals[j] - prev;
                inv_deg[idx] = 1.0f / (float)(v > 1 ? v : 1);
            }
        }
        __syncthreads();
    }
    if (threadIdx.x == 0) row_ptr[n] = carry_s;
}

// ---------------- CSR fill (counting sort by dst) ----------------
__global__ void gnn_csr_fill(const int* __restrict__ src, const int* __restrict__ dst,
                             int* __restrict__ cursor, int* __restrict__ csr_src, int E) {
    int e = blockIdx.x * blockDim.x + threadIdx.x;
    if (e < E) {
        int d = dst[e];
        int p = atomicAdd(&cursor[d], 1);
        csr_src[p] = src[e];
    }
}

// ---------------- fused SAGE layer: mean-agg + lin_l + lin_r + bias + relu ----------------
// one wave per node, lane = feature; unroll-8 gather for memory-level parallelism
__global__ __launch_bounds__(256) void gnn_sage(const float* __restrict__ hin,
                                                float* __restrict__ hout,
                                                const int* __restrict__ row_ptr,
                                                const int* __restrict__ csr_src,
                                                const float* __restrict__ inv_deg,
                                                const float* __restrict__ Wl,
                                                const float* __restrict__ bl,
                                                const float* __restrict__ Wr, int n) {
    __shared__ float2 Wc[64 * 64];  // interleaved {Wl, Wr} -> 32 KiB
    int tid = threadIdx.x;
    for (int i = tid; i < 4096; i += 256) {
        Wc[i].x = Wl[i];
        Wc[i].y = Wr[i];
    }
    __syncthreads();
    int lane = tid & 63, wv = tid >> 6;
    int gw = blockIdx.x * WPB + wv;
    int nw = gridDim.x * WPB;
    for (int nd = gw; nd < n; nd += nw) {
        int s0 = row_ptr[nd], s1 = row_ptr[nd + 1];
        float hr = hin[(size_t)nd * 64 + lane];  // issue root load early
        float acc = 0.0f;
        for (int base = s0; base < s1; base += 64) {
            int cnt = min(64, s1 - base);
            // coalesced load of up to 64 edge indices, broadcast via shfl
            int eidx = (lane < cnt) ? csr_src[base + lane] : 0;
            int i = 0;
            for (; i + 8 <= cnt; i += 8) {
                int i0 = __shfl(eidx, i + 0);
                int i1 = __shfl(eidx, i + 1);
                int i2 = __shfl(eidx, i + 2);
                int i3 = __shfl(eidx, i + 3);
                int i4 = __shfl(eidx, i + 4);
                int i5 = __shfl(eidx, i + 5);
                int i6 = __shfl(eidx, i + 6);
                int i7 = __shfl(eidx, i + 7);
                float v0 = hin[(size_t)i0 * 64 + lane];
                float v1 = hin[(size_t)i1 * 64 + lane];
                float v2 = hin[(size_t)i2 * 64 + lane];
                float v3 = hin[(size_t)i3 * 64 + lane];
                float v4 = hin[(size_t)i4 * 64 + lane];
                float v5 = hin[(size_t)i5 * 64 + lane];
                float v6 = hin[(size_t)i6 * 64 + lane];
                float v7 = hin[(size_t)i7 * 64 + lane];
                acc += ((v0 + v1) + (v2 + v3)) + ((v4 + v5) + (v6 + v7));
            }
            for (; i < cnt; i++) {
                int s = __shfl(eidx, i);
                acc += hin[(size_t)s * 64 + lane];
            }
        }
        acc *= inv_deg[nd];
        float out = bl[lane];
#pragma unroll
        for (int k = 0; k < 64; k++) {
            float a = __shfl(acc, k);
            float h2 = __shfl(hr, k);
            float2 w = Wc[k * 64 + lane];
            out += a * w.x + h2 * w.y;
        }
        hout[(size_t)nd * 64 + lane] = fmaxf(out, 0.0f);
    }
}

// ---------------- global mean pool (batch is sorted) ----------------
__global__ __launch_bounds__(256) void gnn_pool(const float* __restrict__ h,
                                                const int* __restrict__ batch,
                                                float* __restrict__ gsum,
                                                float* __restrict__ gcnt, int n) {
    int lane = threadIdx.x & 63, wv = threadIdx.x >> 6;
    int gw = blockIdx.x * WPB + wv;
    int start = gw * 64;
    if (start >= n) return;
    int cnt_here = min(64, n - start);
    int bi = start + lane;
    if (bi >= n) bi = n - 1;
    int myb = batch[bi];
    int b_first = __shfl(myb, 0);
    int b_last = __shfl(myb, cnt_here - 1);
    if (b_first == b_last && cnt_here == 64) {
        // fast path: whole chunk belongs to one graph -> streaming unroll-8 sum
        float a0 = 0, a1 = 0, a2 = 0, a3 = 0, a4 = 0, a5 = 0, a6 = 0, a7 = 0;
        const float* p = h + (size_t)start * 64 + lane;
#pragma unroll
        for (int i = 0; i < 64; i += 8) {
            a0 += p[(i + 0) * 64];
            a1 += p[(i + 1) * 64];
            a2 += p[(i + 2) * 64];
            a3 += p[(i + 3) * 64];
            a4 += p[(i + 4) * 64];
            a5 += p[(i + 5) * 64];
            a6 += p[(i + 6) * 64];
            a7 += p[(i + 7) * 64];
        }
        float acc = ((a0 + a1) + (a2 + a3)) + ((a4 + a5) + (a6 + a7));
        atomicAdd(&gsum[b_first * 64 + lane], acc);
        if (lane == 0) atomicAdd(&gcnt[b_first], 64.0f);
        return;
    }
    float acc = 0.0f;
    int cnt = 0;
    int cur = b_first;
    for (int i = 0; i < cnt_here; i++) {
        int g = __shfl(myb, i);
        if (g != cur) {
            atomicAdd(&gsum[cur * 64 + lane], acc);
            if (lane == 0) atomicAdd(&gcnt[cur], (float)cnt);
            acc = 0.0f;
            cnt = 0;
            cur = g;
        }
        acc += h[(size_t)(start + i) * 64 + lane];
        cnt++;
    }
    atomicAdd(&gsum[cur * 64 + lane], acc);
    if (lane == 0) atomicAdd(&gcnt[cur], (float)cnt);
}

// ---------------- head: mean, relu(g@l0W+b), @outW+b ----------------
__global__ __launch_bounds__(256) void gnn_head(const float* __restrict__ gsum,
                                                const float* __restrict__ gcnt,
                                                const float* __restrict__ l0W,
                                                const float* __restrict__ l0b,
                                                const float* __restrict__ outW,
                                                const float* __restrict__ outb,
                                                float* __restrict__ out, int G, int OUT) {
    __shared__ float gm[64 * 64];
    __shared__ float t2[64 * 64];
    int tid = threadIdx.x;
    for (int i = tid; i < G * 64; i += 256) {
        int r = i >> 6;
        gm[i] = gsum[i] / fmaxf(gcnt[r], 1.0f);
    }
    __syncthreads();
    for (int i = tid; i < G * 64; i += 256) {
        int r = i >> 6, c = i & 63;
        float s = l0b[c];
#pragma unroll 8
        for (int k = 0; k < 64; k++) s += gm[(r << 6) + k] * l0W[(k << 6) + c];
        t2[i] = fmaxf(s, 0.0f);
    }
    __syncthreads();
    for (int i = tid; i < G * OUT; i += 256) {
        int r = i / OUT, c = i - r * OUT;
        float s = outb[c];
#pragma unroll 8
        for (int k = 0; k < 64; k++) s += t2[(r << 6) + k] * outW[k * OUT + c];
        out[i] = s;
    }
}

extern "C" void kernel_launch(void* const* d_in, const int* in_sizes, int n_in,
                              void* d_out, int out_size, void* d_ws, size_t ws_size,
                              hipStream_t stream) {
    const float* x = (const float*)d_in[0];
    const int* ei = (const int*)d_in[1];
    const int* batch = (const int*)d_in[2];
    const float* Wl[3] = {(const float*)d_in[3], (const float*)d_in[6], (const float*)d_in[9]};
    const float* bl[3] = {(const float*)d_in[4], (const float*)d_in[7], (const float*)d_in[10]};
    const float* Wr[3] = {(const float*)d_in[5], (const float*)d_in[8], (const float*)d_in[11]};
    const float* l0W = (const float*)d_in[12];
    const float* l0b = (const float*)d_in[13];
    const float* outW = (const float*)d_in[14];
    const float* outb = (const float*)d_in[15];

    int N = in_sizes[2];
    int E = in_sizes[1] / 2;
    int OUT = 10;
    int G = out_size / OUT;
    const int* src = ei;
    const int* dst = ei + E;

    char* ws = (char*)d_ws;
    size_t off = 0;
    auto alloc = [&](size_t b) -> char* {
        char* p = ws + off;
        off = (off + b + 255) & ~(size_t)255;
        return p;
    };
    int* degi = (int*)alloc((size_t)N * 4);
    int* row_ptr = (int*)alloc((size_t)(N + 1) * 4);
    int* cursor = (int*)alloc((size_t)N * 4);
    int* csr_src = (int*)alloc((size_t)E * 4);
    float* inv_deg = (float*)alloc((size_t)N * 4);
    float* hA = (float*)alloc((size_t)N * 64 * 4);
    float* hB = (float*)alloc((size_t)N * 64 * 4);
    float* gsum = (float*)alloc((size_t)G * 64 * 4);
    float* gcnt = (float*)alloc((size_t)G * 4);

    hipMemsetAsync(degi, 0, (size_t)N * 4, stream);
    hipMemsetAsync(gsum, 0, (size_t)G * 64 * 4, stream);
    hipMemsetAsync(gcnt, 0, (size_t)G * 4, stream);

    gnn_deg_count<<<(E + 255) / 256, 256, 0, stream>>>(dst, degi, E);
    gnn_scan<<<1, 1024, 0, stream>>>(degi, row_ptr, cursor, inv_deg, N);
    gnn_csr_fill<<<(E + 255) / 256, 256, 0, stream>>>(src, dst, cursor, csr_src, E);

    gnn_sage<<<1280, 256, 0, stream>>>(x, hA, row_ptr, csr_src, inv_deg, Wl[0], bl[0], Wr[0], N);
    gnn_sage<<<1280, 256, 0, stream>>>(hA, hB, row_ptr, csr_src, inv_deg, Wl[1], bl[1], Wr[1], N);
    gnn_sage<<<1280, 256, 0, stream>>>(hB, hA, row_ptr, csr_src, inv_deg, Wl[2], bl[2], Wr[2], N);

    int pool_blocks = ((N + 63) / 64 + WPB - 1) / WPB;
    gnn_pool<<<pool_blocks, 256, 0, stream>>>(hA, batch, gsum, gcnt, N);
    gnn_head<<<1, 256, 0, stream>>>(gsum, gcnt, l0W, l0b, outW, outb, (float*)d_out, G, OUT);
}

// Round 3
// 920.748 us; speedup vs baseline: 1.7035x; 1.3977x over previous
//
#include <hip/hip_runtime.h>
#include <hip/hip_fp16.h>

#define WPB 4  // waves per block (256 threads)
#define SCAN_PT 8
#define SCAN_TPB 256
#define SCAN_CHUNK (SCAN_PT * SCAN_TPB)  // 2048 elems per scan block

// ---------------- f32 -> f16 convert (vectorized) ----------------
__global__ void gnn_cvt(const float4* __restrict__ in, ushort4* __restrict__ out, int n4) {
    int i = blockIdx.x * blockDim.x + threadIdx.x;
    if (i < n4) {
        float4 f = in[i];
        ushort4 o;
        o.x = __half_as_ushort(__float2half(f.x));
        o.y = __half_as_ushort(__float2half(f.y));
        o.z = __half_as_ushort(__float2half(f.z));
        o.w = __half_as_ushort(__float2half(f.w));
        out[i] = o;
    }
}

// ---------------- degree count ----------------
__global__ void gnn_deg_count(const int* __restrict__ dst, int* __restrict__ degi, int E) {
    int e = blockIdx.x * blockDim.x + threadIdx.x;
    if (e < E) atomicAdd(&degi[dst[e]], 1);
}

// ---------------- scan phase A: per-block local exclusive scan + block sums ----------------
__global__ __launch_bounds__(SCAN_TPB) void gnn_scan_a(const int* __restrict__ degi,
                                                       int* __restrict__ loc,
                                                       int* __restrict__ blk_sum,
                                                       float* __restrict__ inv_deg, int n) {
    __shared__ int wsum[4];
    int tid = threadIdx.x, lane = tid & 63, wv = tid >> 6;
    int base = blockIdx.x * SCAN_CHUNK + tid * SCAN_PT;
    int vals[SCAN_PT];
    int run = 0;
#pragma unroll
    for (int j = 0; j < SCAN_PT; j++) {
        int idx = base + j;
        int v = 0;
        if (idx < n) {
            v = degi[idx];
            inv_deg[idx] = 1.0f / (float)(v > 1 ? v : 1);
        }
        run += v;
        vals[j] = run;  // inclusive within thread
    }
    int x = run;
#pragma unroll
    for (int off = 1; off < 64; off <<= 1) {
        int y = __shfl_up(x, off);
        if (lane >= off) x += y;
    }
    if (lane == 63) wsum[wv] = x;
    __syncthreads();
    int wexcl = 0;
    for (int w = 0; w < wv; w++) wexcl += wsum[w];
    int texcl = wexcl + (x - run);
#pragma unroll
    for (int j = 0; j < SCAN_PT; j++) {
        int idx = base + j;
        if (idx < n) {
            int prev = (j == 0) ? 0 : vals[j - 1];
            loc[idx] = texcl + prev;
        }
    }
    if (tid == 0) blk_sum[blockIdx.x] = wsum[0] + wsum[1] + wsum[2] + wsum[3];
}

// ---------------- scan phase B: scan of block sums (1 wave) ----------------
__global__ void gnn_scan_b(const int* __restrict__ blk_sum, int* __restrict__ blk_off,
                           int* __restrict__ row_ptr, int nb, int n) {
    int lane = threadIdx.x;
    int carry = 0;
    for (int base = 0; base < nb; base += 64) {
        int idx = base + lane;
        int v = (idx < nb) ? blk_sum[idx] : 0;
        int x = v;
#pragma unroll
        for (int off = 1; off < 64; off <<= 1) {
            int y = __shfl_up(x, off);
            if (lane >= off) x += y;
        }
        if (idx < nb) blk_off[idx] = carry + (x - v);
        carry += __shfl(x, 63);
    }
    if (lane == 0) row_ptr[n] = carry;
}

// ---------------- scan phase C: add block offsets -> row_ptr, cursor ----------------
__global__ void gnn_scan_c(const int* __restrict__ loc, const int* __restrict__ blk_off,
                           int* __restrict__ row_ptr, int* __restrict__ cursor, int n) {
    int i = blockIdx.x * blockDim.x + threadIdx.x;
    if (i < n) {
        int v = loc[i] + blk_off[i / SCAN_CHUNK];
        row_ptr[i] = v;
        cursor[i] = v;
    }
}

// ---------------- CSR fill (counting sort by dst) ----------------
__global__ void gnn_csr_fill(const int* __restrict__ src, const int* __restrict__ dst,
                             int* __restrict__ cursor, int* __restrict__ csr_src, int E) {
    int e = blockIdx.x * blockDim.x + threadIdx.x;
    if (e < E) {
        int d = dst[e];
        int p = atomicAdd(&cursor[d], 1);
        csr_src[p] = src[e];
    }
}

// ---------------- fused SAGE layer (fp16 in/out, f32 compute) ----------------
// one wave per node, lane = feature; fully-predicated 16-deep parallel gather batches
__global__ __launch_bounds__(256) void gnn_sage(const __half* __restrict__ hin,
                                                __half* __restrict__ hout,
                                                const int* __restrict__ row_ptr,
                                                const int* __restrict__ csr_src,
                                                const float* __restrict__ inv_deg,
                                                const float* __restrict__ Wl,
                                                const float* __restrict__ bl,
                                                const float* __restrict__ Wr, int n) {
    __shared__ float2 Wc[64 * 64];  // interleaved {Wl, Wr} -> 32 KiB
    int tid = threadIdx.x;
    for (int i = tid; i < 4096; i += 256) {
        Wc[i].x = Wl[i];
        Wc[i].y = Wr[i];
    }
    __syncthreads();
    int lane = tid & 63, wv = tid >> 6;
    int gw = blockIdx.x * WPB + wv;
    int nw = gridDim.x * WPB;
    float bias = bl[lane];
    for (int nd = gw; nd < n; nd += nw) {
        int s0 = row_ptr[nd], s1 = row_ptr[nd + 1];
        float idg = inv_deg[nd];
        float hr = __half2float(hin[(size_t)nd * 64 + lane]);
        float acc = 0.0f;
        for (int base = s0; base < s1; base += 64) {
            int cnt = min(64, s1 - base);
            // coalesced load of up to 64 edge indices; pad with safe self-index
            int eidx = (lane < cnt) ? csr_src[base + lane] : nd;
#pragma unroll
            for (int ib = 0; ib < 4; ib++) {
                const int i = ib * 16;
                if (i < cnt) {
                    float v[16];
#pragma unroll
                    for (int j = 0; j < 16; j++) {
                        int sj = __shfl(eidx, i + j);  // const lane -> v_readlane
                        float hv = __half2float(hin[(size_t)sj * 64 + lane]);
                        v[j] = (i + j < cnt) ? hv : 0.0f;
                    }
                    acc += ((((v[0] + v[1]) + (v[2] + v[3])) + ((v[4] + v[5]) + (v[6] + v[7]))) +
                            (((v[8] + v[9]) + (v[10] + v[11])) + ((v[12] + v[13]) + (v[14] + v[15]))));
                }
            }
        }
        acc *= idg;
        float out = bias;
#pragma unroll
        for (int k = 0; k < 64; k++) {
            float a = __shfl(acc, k);
            float h2 = __shfl(hr, k);
            float2 w = Wc[k * 64 + lane];
            out = fmaf(a, w.x, out);
            out = fmaf(h2, w.y, out);
        }
        hout[(size_t)nd * 64 + lane] = __float2half(fmaxf(out, 0.0f));
    }
}

// ---------------- global mean pool (batch is sorted, h is fp16) ----------------
__global__ __launch_bounds__(256) void gnn_pool(const __half* __restrict__ h,
                                                const int* __restrict__ batch,
                                                float* __restrict__ gsum,
                                                float* __restrict__ gcnt, int n) {
    int lane = threadIdx.x & 63, wv = threadIdx.x >> 6;
    int gw = blockIdx.x * WPB + wv;
    int start = gw * 64;
    if (start >= n) return;
    int cnt_here = min(64, n - start);
    int bi = start + lane;
    if (bi >= n) bi = n - 1;
    int myb = batch[bi];
    int b_first = __shfl(myb, 0);
    int b_last = __shfl(myb, cnt_here - 1);
    if (b_first == b_last && cnt_here == 64) {
        float a0 = 0, a1 = 0, a2 = 0, a3 = 0, a4 = 0, a5 = 0, a6 = 0, a7 = 0;
        const __half* p = h + (size_t)start * 64 + lane;
#pragma unroll
        for (int i = 0; i < 64; i += 8) {
            a0 += __half2float(p[(i + 0) * 64]);
            a1 += __half2float(p[(i + 1) * 64]);
            a2 += __half2float(p[(i + 2) * 64]);
            a3 += __half2float(p[(i + 3) * 64]);
            a4 += __half2float(p[(i + 4) * 64]);
            a5 += __half2float(p[(i + 5) * 64]);
            a6 += __half2float(p[(i + 6) * 64]);
            a7 += __half2float(p[(i + 7) * 64]);
        }
        float acc = ((a0 + a1) + (a2 + a3)) + ((a4 + a5) + (a6 + a7));
        atomicAdd(&gsum[b_first * 64 + lane], acc);
        if (lane == 0) atomicAdd(&gcnt[b_first], 64.0f);
        return;
    }
    float acc = 0.0f;
    int cnt = 0;
    int cur = b_first;
    for (int i = 0; i < cnt_here; i++) {
        int g = __shfl(myb, i);
        if (g != cur) {
            atomicAdd(&gsum[cur * 64 + lane], acc);
            if (lane == 0) atomicAdd(&gcnt[cur], (float)cnt);
            acc = 0.0f;
            cnt = 0;
            cur = g;
        }
        acc += __half2float(h[(size_t)(start + i) * 64 + lane]);
        cnt++;
    }
    atomicAdd(&gsum[cur * 64 + lane], acc);
    if (lane == 0) atomicAdd(&gcnt[cur], (float)cnt);
}

// ---------------- head: mean, relu(g@l0W+b), @outW+b ----------------
__global__ __launch_bounds__(256) void gnn_head(const float* __restrict__ gsum,
                                                const float* __restrict__ gcnt,
                                                const float* __restrict__ l0W,
                                                const float* __restrict__ l0b,
                                                const float* __restrict__ outW,
                                                const float* __restrict__ outb,
                                                float* __restrict__ out, int G, int OUT) {
    __shared__ float gm[64 * 64];
    __shared__ float t2[64 * 64];
    int tid = threadIdx.x;
    for (int i = tid; i < G * 64; i += 256) {
        int r = i >> 6;
        gm[i] = gsum[i] / fmaxf(gcnt[r], 1.0f);
    }
    __syncthreads();
    for (int i = tid; i < G * 64; i += 256) {
        int r = i >> 6, c = i & 63;
        float s = l0b[c];
#pragma unroll 8
        for (int k = 0; k < 64; k++) s += gm[(r << 6) + k] * l0W[(k << 6) + c];
        t2[i] = fmaxf(s, 0.0f);
    }
    __syncthreads();
    for (int i = tid; i < G * OUT; i += 256) {
        int r = i / OUT, c = i - r * OUT;
        float s = outb[c];
#pragma unroll 8
        for (int k = 0; k < 64; k++) s += t2[(r << 6) + k] * outW[k * OUT + c];
        out[i] = s;
    }
}

extern "C" void kernel_launch(void* const* d_in, const int* in_sizes, int n_in,
                              void* d_out, int out_size, void* d_ws, size_t ws_size,
                              hipStream_t stream) {
    const float* x = (const float*)d_in[0];
    const int* ei = (const int*)d_in[1];
    const int* batch = (const int*)d_in[2];
    const float* Wl[3] = {(const float*)d_in[3], (const float*)d_in[6], (const float*)d_in[9]};
    const float* bl[3] = {(const float*)d_in[4], (const float*)d_in[7], (const float*)d_in[10]};
    const float* Wr[3] = {(const float*)d_in[5], (const float*)d_in[8], (const float*)d_in[11]};
    const float* l0W = (const float*)d_in[12];
    const float* l0b = (const float*)d_in[13];
    const float* outW = (const float*)d_in[14];
    const float* outb = (const float*)d_in[15];

    int N = in_sizes[2];
    int E = in_sizes[1] / 2;
    int OUT = 10;
    int G = out_size / OUT;
    const int* src = ei;
    const int* dst = ei + E;

    char* ws = (char*)d_ws;
    size_t off = 0;
    auto alloc = [&](size_t b) -> char* {
        char* p = ws + off;
        off = (off + b + 255) & ~(size_t)255;
        return p;
    };
    int NB = (N + SCAN_CHUNK - 1) / SCAN_CHUNK;
    int* degi = (int*)alloc((size_t)N * 4);
    int* row_ptr = (int*)alloc((size_t)(N + 1) * 4);
    int* cursor = (int*)alloc((size_t)N * 4);
    int* csr_src = (int*)alloc((size_t)E * 4);
    float* inv_deg = (float*)alloc((size_t)N * 4);
    int* loc = (int*)alloc((size_t)N * 4);
    int* blk_sum = (int*)alloc((size_t)NB * 4);
    int* blk_off = (int*)alloc((size_t)NB * 4);
    __half* x16 = (__half*)alloc((size_t)N * 64 * 2);
    __half* hA = (__half*)alloc((size_t)N * 64 * 2);
    __half* hB = (__half*)alloc((size_t)N * 64 * 2);
    float* gsum = (float*)alloc((size_t)G * 64 * 4);
    float* gcnt = (float*)alloc((size_t)G * 4);

    hipMemsetAsync(degi, 0, (size_t)N * 4, stream);
    hipMemsetAsync(gsum, 0, (size_t)G * 64 * 4, stream);
    hipMemsetAsync(gcnt, 0, (size_t)G * 4, stream);

    int n4 = N * 64 / 4;
    gnn_cvt<<<(n4 + 255) / 256, 256, 0, stream>>>((const float4*)x, (ushort4*)x16, n4);
    gnn_deg_count<<<(E + 255) / 256, 256, 0, stream>>>(dst, degi, E);
    gnn_scan_a<<<NB, SCAN_TPB, 0, stream>>>(degi, loc, blk_sum, inv_deg, N);
    gnn_scan_b<<<1, 64, 0, stream>>>(blk_sum, blk_off, row_ptr, NB, N);
    gnn_scan_c<<<(N + 255) / 256, 256, 0, stream>>>(loc, blk_off, row_ptr, cursor, N);
    gnn_csr_fill<<<(E + 255) / 256, 256, 0, stream>>>(src, dst, cursor, csr_src, E);

    gnn_sage<<<1024, 256, 0, stream>>>(x16, hA, row_ptr, csr_src, inv_deg, Wl[0], bl[0], Wr[0], N);
    gnn_sage<<<1024, 256, 0, stream>>>(hA, hB, row_ptr, csr_src, inv_deg, Wl[1], bl[1], Wr[1], N);
    gnn_sage<<<1024, 256, 0, stream>>>(hB, hA, row_ptr, csr_src, inv_deg, Wl[2], bl[2], Wr[2], N);

    int pool_blocks = ((N + 63) / 64 + WPB - 1) / WPB;
    gnn_pool<<<pool_blocks, 256, 0, stream>>>(hA, batch, gsum, gcnt, N);
    gnn_head<<<1, 256, 0, stream>>>(gsum, gcnt, l0W, l0b, outW, outb, (float*)d_out, G, OUT);
}

// Round 4
// 607.636 us; speedup vs baseline: 2.5812x; 1.5153x over previous
//
#include <hip/hip_runtime.h>
#include <hip/hip_fp16.h>

#define WPB 4  // waves per block (256 threads)
#define SCAN_PT 8
#define SCAN_TPB 256
#define SCAN_CHUNK (SCAN_PT * SCAN_TPB)  // 2048 elems per scan block
#define PADK 136                         // f16 elems per LDS row: 128 + 8 pad (16B-aligned rows)

typedef _Float16 half8 __attribute__((ext_vector_type(8)));
typedef float floatx4 __attribute__((ext_vector_type(4)));

// ---------------- f32 -> f16 convert (vectorized) ----------------
__global__ void gnn_cvt(const float4* __restrict__ in, ushort4* __restrict__ out, int n4) {
    int i = blockIdx.x * blockDim.x + threadIdx.x;
    if (i < n4) {
        float4 f = in[i];
        ushort4 o;
        o.x = __half_as_ushort(__float2half(f.x));
        o.y = __half_as_ushort(__float2half(f.y));
        o.z = __half_as_ushort(__float2half(f.z));
        o.w = __half_as_ushort(__float2half(f.w));
        out[i] = o;
    }
}

// ---------------- degree count ----------------
__global__ void gnn_deg_count(const int* __restrict__ dst, int* __restrict__ degi, int E) {
    int e = blockIdx.x * blockDim.x + threadIdx.x;
    if (e < E) atomicAdd(&degi[dst[e]], 1);
}

// ---------------- scan phase A ----------------
__global__ __launch_bounds__(SCAN_TPB) void gnn_scan_a(const int* __restrict__ degi,
                                                       int* __restrict__ loc,
                                                       int* __restrict__ blk_sum,
                                                       float* __restrict__ inv_deg, int n) {
    __shared__ int wsum[4];
    int tid = threadIdx.x, lane = tid & 63, wv = tid >> 6;
    int base = blockIdx.x * SCAN_CHUNK + tid * SCAN_PT;
    int vals[SCAN_PT];
    int run = 0;
#pragma unroll
    for (int j = 0; j < SCAN_PT; j++) {
        int idx = base + j;
        int v = 0;
        if (idx < n) {
            v = degi[idx];
            inv_deg[idx] = 1.0f / (float)(v > 1 ? v : 1);
        }
        run += v;
        vals[j] = run;
    }
    int x = run;
#pragma unroll
    for (int off = 1; off < 64; off <<= 1) {
        int y = __shfl_up(x, off);
        if (lane >= off) x += y;
    }
    if (lane == 63) wsum[wv] = x;
    __syncthreads();
    int wexcl = 0;
    for (int w = 0; w < wv; w++) wexcl += wsum[w];
    int texcl = wexcl + (x - run);
#pragma unroll
    for (int j = 0; j < SCAN_PT; j++) {
        int idx = base + j;
        if (idx < n) {
            int prev = (j == 0) ? 0 : vals[j - 1];
            loc[idx] = texcl + prev;
        }
    }
    if (tid == 0) blk_sum[blockIdx.x] = wsum[0] + wsum[1] + wsum[2] + wsum[3];
}

// ---------------- scan phase B ----------------
__global__ void gnn_scan_b(const int* __restrict__ blk_sum, int* __restrict__ blk_off,
                           int* __restrict__ row_ptr, int nb, int n) {
    int lane = threadIdx.x;
    int carry = 0;
    for (int base = 0; base < nb; base += 64) {
        int idx = base + lane;
        int v = (idx < nb) ? blk_sum[idx] : 0;
        int x = v;
#pragma unroll
        for (int off = 1; off < 64; off <<= 1) {
            int y = __shfl_up(x, off);
            if (lane >= off) x += y;
        }
        if (idx < nb) blk_off[idx] = carry + (x - v);
        carry += __shfl(x, 63);
    }
    if (lane == 0) row_ptr[n] = carry;
}

// ---------------- scan phase C ----------------
__global__ void gnn_scan_c(const int* __restrict__ loc, const int* __restrict__ blk_off,
                           int* __restrict__ row_ptr, int* __restrict__ cursor, int n) {
    int i = blockIdx.x * blockDim.x + threadIdx.x;
    if (i < n) {
        int v = loc[i] + blk_off[i / SCAN_CHUNK];
        row_ptr[i] = v;
        cursor[i] = v;
    }
}

// ---------------- CSR fill ----------------
__global__ void gnn_csr_fill(const int* __restrict__ src, const int* __restrict__ dst,
                             int* __restrict__ cursor, int* __restrict__ csr_src, int E) {
    int e = blockIdx.x * blockDim.x + threadIdx.x;
    if (e < E) {
        int d = dst[e];
        int p = atomicAdd(&cursor[d], 1);
        csr_src[p] = src[e];
    }
}

// ---------------- fused SAGE layer (fp16, MFMA matmul) ----------------
// one wave per 16-node group: gather-mean into LDS tile [16 x 128],
// then [16x128] @ [128x64] via 16x mfma_f32_16x16x32_f16.
__global__ __launch_bounds__(256) void gnn_sage(const __half* __restrict__ hin,
                                                __half* __restrict__ hout,
                                                const int* __restrict__ row_ptr,
                                                const int* __restrict__ csr_src,
                                                const float* __restrict__ inv_deg,
                                                const float* __restrict__ Wl,
                                                const float* __restrict__ bl,
                                                const float* __restrict__ Wr, int n) {
    __shared__ _Float16 w_lds[64 * PADK];       // W2^T: [n][k], k = [Wl | Wr], 17408 B
    __shared__ _Float16 in_lds[WPB][16 * PADK]; // per-wave [m][k] tile, 4352 B each
    int tid = threadIdx.x, lane = tid & 63, wv = tid >> 6;
    // stage W2^T (k-major rows per output feature n)
    for (int i = tid; i < 64 * 64; i += 256) {
        int k = i >> 6, nn = i & 63;
        float wl = Wl[i], wr = Wr[i];
        w_lds[nn * PADK + k] = (_Float16)wl;
        w_lds[nn * PADK + 64 + k] = (_Float16)wr;
    }
    __syncthreads();
    int m16 = lane & 15, quad = lane >> 4;
    float bias[4];
#pragma unroll
    for (int nt = 0; nt < 4; nt++) bias[nt] = bl[nt * 16 + m16];
    _Float16* my_in = in_lds[wv];
    const _Float16* hin16 = (const _Float16*)hin;
    int ngroups = (n + 15) >> 4;
    int gw = blockIdx.x * WPB + wv;
    int nw = gridDim.x * WPB;
    for (int g = gw; g < ngroups; g += nw) {
        int nd0 = g << 4;
        // ---- gather phase: 16 nodes, lane = feature ----
        for (int j2 = 0; j2 < 16; j2++) {
            int nd = nd0 + j2;
            if (nd >= n) nd = n - 1;
            int s0 = row_ptr[nd], s1 = row_ptr[nd + 1];
            float idg = inv_deg[nd];
            // root features -> K = 64..127
            my_in[j2 * PADK + 64 + lane] = hin16[(size_t)nd * 64 + lane];
            float acc = 0.0f;
            for (int base = s0; base < s1; base += 64) {
                int cnt = min(64, s1 - base);
                int eidx = (lane < cnt) ? csr_src[base + lane] : nd;
#pragma unroll
                for (int ib = 0; ib < 4; ib++) {
                    const int i = ib * 16;
                    if (i < cnt) {
                        float v[16];
#pragma unroll
                        for (int j = 0; j < 16; j++) {
                            int sj = __shfl(eidx, i + j);  // const lane -> readlane
                            float hv = __half2float(hin[(size_t)sj * 64 + lane]);
                            v[j] = (i + j < cnt) ? hv : 0.0f;
                        }
                        acc += ((((v[0] + v[1]) + (v[2] + v[3])) + ((v[4] + v[5]) + (v[6] + v[7]))) +
                                (((v[8] + v[9]) + (v[10] + v[11])) + ((v[12] + v[13]) + (v[14] + v[15]))));
                    }
                }
            }
            // mean-agg -> K = 0..63
            my_in[j2 * PADK + lane] = (_Float16)(acc * idg);
        }
        // ---- MFMA phase: D[16 nodes][64 feats] = A[16][128] * B[128][64] ----
        // A: m = lane&15 (node), k = quad*8+j ; B: n = lane&15, k = quad*8+j
        half8 afrag[4];
        const _Float16* abase = my_in + m16 * PADK + quad * 8;
#pragma unroll
        for (int ks = 0; ks < 4; ks++) afrag[ks] = *(const half8*)(abase + ks * 32);
        floatx4 accv[4];
#pragma unroll
        for (int nt = 0; nt < 4; nt++) {
            accv[nt].x = 0.f; accv[nt].y = 0.f; accv[nt].z = 0.f; accv[nt].w = 0.f;
        }
#pragma unroll
        for (int nt = 0; nt < 4; nt++) {
            const _Float16* bbase = w_lds + (nt * 16 + m16) * PADK + quad * 8;
#pragma unroll
            for (int ks = 0; ks < 4; ks++) {
                half8 bfrag = *(const half8*)(bbase + ks * 32);
                accv[nt] = __builtin_amdgcn_mfma_f32_16x16x32_f16(afrag[ks], bfrag, accv[nt], 0, 0, 0);
            }
        }
        // ---- epilogue: D col=lane&15 (feat), row=quad*4+reg (node) ----
#pragma unroll
        for (int nt = 0; nt < 4; nt++) {
#pragma unroll
            for (int r = 0; r < 4; r++) {
                int node = nd0 + quad * 4 + r;
                if (node < n) {
                    float v = fmaxf(accv[nt][r] + bias[nt], 0.0f);
                    hout[(size_t)node * 64 + nt * 16 + m16] = __float2half(v);
                }
            }
        }
    }
}

// ---------------- global mean pool (batch is sorted, h is fp16) ----------------
__global__ __launch_bounds__(256) void gnn_pool(const __half* __restrict__ h,
                                                const int* __restrict__ batch,
                                                float* __restrict__ gsum,
                                                float* __restrict__ gcnt, int n) {
    int lane = threadIdx.x & 63, wv = threadIdx.x >> 6;
    int gw = blockIdx.x * WPB + wv;
    int start = gw * 64;
    if (start >= n) return;
    int cnt_here = min(64, n - start);
    int bi = start + lane;
    if (bi >= n) bi = n - 1;
    int myb = batch[bi];
    int b_first = __shfl(myb, 0);
    int b_last = __shfl(myb, cnt_here - 1);
    if (b_first == b_last && cnt_here == 64) {
        float a0 = 0, a1 = 0, a2 = 0, a3 = 0, a4 = 0, a5 = 0, a6 = 0, a7 = 0;
        const __half* p = h + (size_t)start * 64 + lane;
#pragma unroll
        for (int i = 0; i < 64; i += 8) {
            a0 += __half2float(p[(i + 0) * 64]);
            a1 += __half2float(p[(i + 1) * 64]);
            a2 += __half2float(p[(i + 2) * 64]);
            a3 += __half2float(p[(i + 3) * 64]);
            a4 += __half2float(p[(i + 4) * 64]);
            a5 += __half2float(p[(i + 5) * 64]);
            a6 += __half2float(p[(i + 6) * 64]);
            a7 += __half2float(p[(i + 7) * 64]);
        }
        float acc = ((a0 + a1) + (a2 + a3)) + ((a4 + a5) + (a6 + a7));
        atomicAdd(&gsum[b_first * 64 + lane], acc);
        if (lane == 0) atomicAdd(&gcnt[b_first], 64.0f);
        return;
    }
    float acc = 0.0f;
    int cnt = 0;
    int cur = b_first;
    for (int i = 0; i < cnt_here; i++) {
        int g = __shfl(myb, i);
        if (g != cur) {
            atomicAdd(&gsum[cur * 64 + lane], acc);
            if (lane == 0) atomicAdd(&gcnt[cur], (float)cnt);
            acc = 0.0f;
            cnt = 0;
            cur = g;
        }
        acc += __half2float(h[(size_t)(start + i) * 64 + lane]);
        cnt++;
    }
    atomicAdd(&gsum[cur * 64 + lane], acc);
    if (lane == 0) atomicAdd(&gcnt[cur], (float)cnt);
}

// ---------------- head ----------------
__global__ __launch_bounds__(256) void gnn_head(const float* __restrict__ gsum,
                                                const float* __restrict__ gcnt,
                                                const float* __restrict__ l0W,
                                                const float* __restrict__ l0b,
                                                const float* __restrict__ outW,
                                                const float* __restrict__ outb,
                                                float* __restrict__ out, int G, int OUT) {
    __shared__ float gm[64 * 64];
    __shared__ float t2[64 * 64];
    int tid = threadIdx.x;
    for (int i = tid; i < G * 64; i += 256) {
        int r = i >> 6;
        gm[i] = gsum[i] / fmaxf(gcnt[r], 1.0f);
    }
    __syncthreads();
    for (int i = tid; i < G * 64; i += 256) {
        int r = i >> 6, c = i & 63;
        float s = l0b[c];
#pragma unroll 8
        for (int k = 0; k < 64; k++) s += gm[(r << 6) + k] * l0W[(k << 6) + c];
        t2[i] = fmaxf(s, 0.0f);
    }
    __syncthreads();
    for (int i = tid; i < G * OUT; i += 256) {
        int r = i / OUT, c = i - r * OUT;
        float s = outb[c];
#pragma unroll 8
        for (int k = 0; k < 64; k++) s += t2[(r << 6) + k] * outW[k * OUT + c];
        out[i] = s;
    }
}

extern "C" void kernel_launch(void* const* d_in, const int* in_sizes, int n_in,
                              void* d_out, int out_size, void* d_ws, size_t ws_size,
                              hipStream_t stream) {
    const float* x = (const float*)d_in[0];
    const int* ei = (const int*)d_in[1];
    const int* batch = (const int*)d_in[2];
    const float* Wl[3] = {(const float*)d_in[3], (const float*)d_in[6], (const float*)d_in[9]};
    const float* bl[3] = {(const float*)d_in[4], (const float*)d_in[7], (const float*)d_in[10]};
    const float* Wr[3] = {(const float*)d_in[5], (const float*)d_in[8], (const float*)d_in[11]};
    const float* l0W = (const float*)d_in[12];
    const float* l0b = (const float*)d_in[13];
    const float* outW = (const float*)d_in[14];
    const float* outb = (const float*)d_in[15];

    int N = in_sizes[2];
    int E = in_sizes[1] / 2;
    int OUT = 10;
    int G = out_size / OUT;
    const int* src = ei;
    const int* dst = ei + E;

    char* ws = (char*)d_ws;
    size_t off = 0;
    auto alloc = [&](size_t b) -> char* {
        char* p = ws + off;
        off = (off + b + 255) & ~(size_t)255;
        return p;
    };
    int NB = (N + SCAN_CHUNK - 1) / SCAN_CHUNK;
    int* degi = (int*)alloc((size_t)N * 4);
    int* row_ptr = (int*)alloc((size_t)(N + 1) * 4);
    int* cursor = (int*)alloc((size_t)N * 4);
    int* csr_src = (int*)alloc((size_t)E * 4);
    float* inv_deg = (float*)alloc((size_t)N * 4);
    int* loc = (int*)alloc((size_t)N * 4);
    int* blk_sum = (int*)alloc((size_t)NB * 4);
    int* blk_off = (int*)alloc((size_t)NB * 4);
    __half* x16 = (__half*)alloc((size_t)N * 64 * 2);
    __half* hA = (__half*)alloc((size_t)N * 64 * 2);
    __half* hB = (__half*)alloc((size_t)N * 64 * 2);
    float* gsum = (float*)alloc((size_t)G * 64 * 4);
    float* gcnt = (float*)alloc((size_t)G * 4);

    hipMemsetAsync(degi, 0, (size_t)N * 4, stream);
    hipMemsetAsync(gsum, 0, (size_t)G * 64 * 4, stream);
    hipMemsetAsync(gcnt, 0, (size_t)G * 4, stream);

    int n4 = N * 64 / 4;
    gnn_cvt<<<(n4 + 255) / 256, 256, 0, stream>>>((const float4*)x, (ushort4*)x16, n4);
    gnn_deg_count<<<(E + 255) / 256, 256, 0, stream>>>(dst, degi, E);
    gnn_scan_a<<<NB, SCAN_TPB, 0, stream>>>(degi, loc, blk_sum, inv_deg, N);
    gnn_scan_b<<<1, 64, 0, stream>>>(blk_sum, blk_off, row_ptr, NB, N);
    gnn_scan_c<<<(N + 255) / 256, 256, 0, stream>>>(loc, blk_off, row_ptr, cursor, N);
    gnn_csr_fill<<<(E + 255) / 256, 256, 0, stream>>>(src, dst, cursor, csr_src, E);

    gnn_sage<<<1024, 256, 0, stream>>>(x16, hA, row_ptr, csr_src, inv_deg, Wl[0], bl[0], Wr[0], N);
    gnn_sage<<<1024, 256, 0, stream>>>(hA, hB, row_ptr, csr_src, inv_deg, Wl[1], bl[1], Wr[1], N);
    gnn_sage<<<1024, 256, 0, stream>>>(hB, hA, row_ptr, csr_src, inv_deg, Wl[2], bl[2], Wr[2], N);

    int pool_blocks = ((N + 63) / 64 + WPB - 1) / WPB;
    gnn_pool<<<pool_blocks, 256, 0, stream>>>(hA, batch, gsum, gcnt, N);
    gnn_head<<<1, 256, 0, stream>>>(gsum, gcnt, l0W, l0b, outW, outb, (float*)d_out, G, OUT);
}